// Round 8
// baseline (3734.047 us; speedup 1.0000x reference)
//
#include <hip/hip_runtime.h>

#define NB 256      // batch
#define TT 1000     // total timesteps
#define HD 128      // hidden
#define NG 512      // 4*H, PyTorch gate order i,f,g,o
#define SS 8        // K2: timesteps per LDS slab

// Keep loaded weights live in VGPRs (asm results can't be rematerialized).
#define PIN4(v) asm("" : "+v"(v.x), "+v"(v.y), "+v"(v.z), "+v"(v.w))

// 1024 thr = 16 waves = 4 waves/SIMD at 1 block/CU. waves_per_eu(4,4) pins the
// scheduler's occupancy target so it has no incentive to squeeze regs below 128.
#define WG_ATTRS __attribute__((amdgpu_flat_work_group_size(1024,1024), amdgpu_waves_per_eu(4,4)))

__device__ __forceinline__ float sigf(float x) {
    return 1.f / (1.f + __expf(-x));
}
__device__ __forceinline__ float tanhfast(float x) {
    float e = __expf(-2.f * x);                 // 2*sigmoid(2x)-1, NaN-safe
    return 2.f / (1.f + e) - 1.f;
}

// ---------------- K1: layer-0 recurrence, row split across lane pairs ----------------
// Thread j: gate row r=j>>1, half hf=j&1 -> 64 weights/thread in VGPRs.
// Halves combine via __shfl_xor(s,1) (same wave) — no extra barrier.
__global__ WG_ATTRS
void lstm_layer0(const float* __restrict__ x,
                 const float* __restrict__ Wih, const float* __restrict__ Whh,
                 const float* __restrict__ bih, const float* __restrict__ bhh,
                 float* __restrict__ h1c,
                 float* __restrict__ hstate, float* __restrict__ cstate,
                 int t0, int len)
{
    __shared__ __align__(16) float h_lds[HD];
    __shared__ float gbuf[NG];
    __shared__ float x_lds[3 * TT];   // 12 KB
    const int j = threadIdx.x;        // 0..1023
    const int b = blockIdx.x;
    const int r = j >> 1;             // gate row 0..511
    const int hf = j & 1;             // half 0/1

    float4 wv[16];   // W_hh[r][hf*64 .. hf*64+63]
    {
        const float4* wr = (const float4*)(Whh + (size_t)r * HD + (hf << 6));
        #pragma unroll
        for (int q = 0; q < 16; ++q) wv[q] = wr[q];
        #pragma unroll
        for (int q = 0; q < 16; ++q) PIN4(wv[q]);
    }
    const float wx0 = Wih[r*3+0], wx1 = Wih[r*3+1], wx2 = Wih[r*3+2];
    const float bias = bih[r] + bhh[r];

    for (int idx = j; idx < 3*len; idx += 1024)
        x_lds[idx] = x[((size_t)b*TT + t0)*3 + idx];

    float c = 0.f, hcur = 0.f;
    if (j < HD) {
        if (t0 != 0) { hcur = hstate[b*HD+j]; c = cstate[b*HD+j]; }
        h_lds[j] = hcur;
    }
    __syncthreads();

    const int gtype = r >> 7;   // 0:i 1:f 2:g 3:o — uniform per 256-thread span
    for (int tc = 0; tc < len; ++tc) {
        float a0=0.f,a1=0.f,a2=0.f,a3=0.f;
        const float4* h4 = ((const float4*)h_lds) + (hf << 4);  // 2-addr broadcast: free
        #pragma unroll
        for (int q = 0; q < 16; ++q) {
            float4 hv = h4[q];
            a0 = fmaf(hv.x, wv[q].x, a0);
            a1 = fmaf(hv.y, wv[q].y, a1);
            a2 = fmaf(hv.z, wv[q].z, a2);
            a3 = fmaf(hv.w, wv[q].w, a3);
        }
        float s = (a0+a1)+(a2+a3);
        s += __shfl_xor(s, 1);          // full 128-dot for row r (both lanes)
        float acc = bias + s;
        acc = fmaf(wx0, x_lds[3*tc+0], acc);
        acc = fmaf(wx1, x_lds[3*tc+1], acc);
        acc = fmaf(wx2, x_lds[3*tc+2], acc);
        float act = (gtype == 2) ? tanhfast(acc) : sigf(acc);
        if (hf == 0) gbuf[r] = act;     // even lanes: consecutive 4B -> conflict-free
        __syncthreads();                 // barrier A: gates visible
        if (j < HD) {
            float ig = gbuf[j], fg = gbuf[HD+j], gg = gbuf[2*HD+j], og = gbuf[3*HD+j];
            c = fmaf(fg, c, ig*gg);
            hcur = og * tanhfast(c);
            h_lds[j] = hcur;
            h1c[((size_t)b*len + tc)*HD + j] = hcur;
        }
        __syncthreads();                 // barrier B: new h visible
    }
    if (j < HD) { hstate[b*HD+j] = hcur; cstate[b*HD+j] = c; }
}

// ---------------- K2: xg1 = h1 @ W_ih_l1^T + biases, row split across lane pairs ----------------
__global__ WG_ATTRS
void xgate_gemm(const float* __restrict__ h1c,
                const float* __restrict__ Wih1,
                const float* __restrict__ bih1, const float* __restrict__ bhh1,
                float* __restrict__ xg1c, int len)
{
    __shared__ __align__(16) float hrows[SS][HD];   // 4 KB
    const int j = threadIdx.x;
    const int b = blockIdx.x;
    const int r = j >> 1;
    const int hf = j & 1;
    float4 wv[16];
    {
        const float4* wr = (const float4*)(Wih1 + (size_t)r * HD + (hf << 6));
        #pragma unroll
        for (int q = 0; q < 16; ++q) wv[q] = wr[q];
        #pragma unroll
        for (int q = 0; q < 16; ++q) PIN4(wv[q]);
    }
    const float bias = bih1[r] + bhh1[r];

    for (int ts = 0; ts < len; ts += SS) {
        const int ns = (len - ts < SS) ? (len - ts) : SS;
        __syncthreads();   // previous slab's reads complete before overwrite
        for (int idx = j; idx < ns * HD; idx += 1024)
            hrows[idx >> 7][idx & 127] = h1c[((size_t)b*len + ts)*HD + idx];
        __syncthreads();   // slab visible
        for (int s = 0; s < ns; ++s) {
            float a0=0.f,a1=0.f,a2=0.f,a3=0.f;
            const float4* h4 = ((const float4*)hrows[s]) + (hf << 4);
            #pragma unroll
            for (int q = 0; q < 16; ++q) {
                float4 hv = h4[q];
                a0=fmaf(hv.x,wv[q].x,a0); a1=fmaf(hv.y,wv[q].y,a1);
                a2=fmaf(hv.z,wv[q].z,a2); a3=fmaf(hv.w,wv[q].w,a3);
            }
            float d = (a0+a1)+(a2+a3);
            d += __shfl_xor(d, 1);
            if (hf == 0)
                xg1c[((size_t)b*len + ts + s)*NG + r] = bias + d;
        }
    }
}

// ---------------- K3: layer-1 recurrence, row split across lane pairs ----------------
__global__ WG_ATTRS
void lstm_layer1(const float* __restrict__ xg1c,
                 const float* __restrict__ Whh1,
                 float* __restrict__ h2c,
                 float* __restrict__ hstate, float* __restrict__ cstate,
                 int t0, int len)
{
    __shared__ __align__(16) float h_lds[HD];
    __shared__ float gbuf[NG];
    const int j = threadIdx.x;
    const int b = blockIdx.x;
    const int r = j >> 1;
    const int hf = j & 1;
    float4 wv[16];   // W_hh_l1[r][hf*64 ..]
    {
        const float4* wr = (const float4*)(Whh1 + (size_t)r * HD + (hf << 6));
        #pragma unroll
        for (int q = 0; q < 16; ++q) wv[q] = wr[q];
        #pragma unroll
        for (int q = 0; q < 16; ++q) PIN4(wv[q]);
    }
    float c = 0.f, hcur = 0.f;
    if (j < HD) {
        if (t0 != 0) { hcur = hstate[b*HD+j]; c = cstate[b*HD+j]; }
        h_lds[j] = hcur;
    }
    __syncthreads();
    const int gtype = r >> 7;
    float xg_cur = xg1c[((size_t)b*len + 0)*NG + r];   // pair loads same word
    for (int tc = 0; tc < len; ++tc) {
        float xg_nxt = 0.f;
        if (tc+1 < len) xg_nxt = xg1c[((size_t)b*len + tc+1)*NG + r]; // prefetch
        float a0=0.f,a1=0.f,a2=0.f,a3=0.f;
        const float4* h4 = ((const float4*)h_lds) + (hf << 4);
        #pragma unroll
        for (int q = 0; q < 16; ++q) {
            float4 hv = h4[q];
            a0=fmaf(hv.x,wv[q].x,a0); a1=fmaf(hv.y,wv[q].y,a1);
            a2=fmaf(hv.z,wv[q].z,a2); a3=fmaf(hv.w,wv[q].w,a3);
        }
        float s = (a0+a1)+(a2+a3);
        s += __shfl_xor(s, 1);
        float acc = xg_cur + s;         // bias already folded in by K2
        float act = (gtype == 2) ? tanhfast(acc) : sigf(acc);
        if (hf == 0) gbuf[r] = act;
        __syncthreads();                 // barrier A
        if (j < HD) {
            float ig = gbuf[j], fg = gbuf[HD+j], gg = gbuf[2*HD+j], og = gbuf[3*HD+j];
            c = fmaf(fg, c, ig*gg);
            hcur = og * tanhfast(c);
            h_lds[j] = hcur;
            h2c[((size_t)b*len + tc)*HD + j] = hcur;
        }
        __syncthreads();                 // barrier B
        xg_cur = xg_nxt;
    }
    if (j < HD) { hstate[b*HD+j] = hcur; cstate[b*HD+j] = c; }
}

// ---------------- K4: y = h2 @ fcw^T + fcb — wave-per-row, deterministic ----------------
__global__ __launch_bounds__(512, 1)
void fc_head(const float* __restrict__ h2c,
             const float* __restrict__ fcw, const float* __restrict__ fcb,
             float* __restrict__ y, int t0, int len)
{
    const int b = blockIdx.x;
    const int wid = threadIdx.x >> 6;   // 0..7
    const int lane = threadIdx.x & 63;
    const float f0a = fcw[0*HD+lane], f0b = fcw[0*HD+64+lane];
    const float f1a = fcw[1*HD+lane], f1b = fcw[1*HD+64+lane];
    const float f2a = fcw[2*HD+lane], f2b = fcw[2*HD+64+lane];
    const float fb = (lane < 3) ? fcb[lane] : 0.f;
    for (int tc = wid; tc < len; tc += 8) {
        const float* hp = h2c + ((size_t)b*len + tc)*HD;
        float ha = hp[lane], hb = hp[64+lane];
        float y0 = ha*f0a + hb*f0b;
        float y1 = ha*f1a + hb*f1b;
        float y2 = ha*f2a + hb*f2b;
        #pragma unroll
        for (int m = 1; m < 64; m <<= 1) {
            y0 += __shfl_xor(y0, m);
            y1 += __shfl_xor(y1, m);
            y2 += __shfl_xor(y2, m);
        }
        if (lane < 3) {
            float yv = (lane==0) ? y0 : (lane==1) ? y1 : y2;
            y[((size_t)b*TT + (t0+tc))*3 + lane] = yv + fb;
        }
    }
}

extern "C" void kernel_launch(void* const* d_in, const int* in_sizes, int n_in,
                              void* d_out, int out_size, void* d_ws, size_t ws_size,
                              hipStream_t stream)
{
    const float* x    = (const float*)d_in[0];
    const float* Wih0 = (const float*)d_in[1];
    const float* Whh0 = (const float*)d_in[2];
    const float* bih0 = (const float*)d_in[3];
    const float* bhh0 = (const float*)d_in[4];
    const float* Wih1 = (const float*)d_in[5];
    const float* Whh1 = (const float*)d_in[6];
    const float* bih1 = (const float*)d_in[7];
    const float* bhh1 = (const float*)d_in[8];
    const float* fcw  = (const float*)d_in[9];
    const float* fcb  = (const float*)d_in[10];
    float* y = (float*)d_out;

    // ws layout: h1 chunk (B*Tc*128 f32) + xg1 chunk (B*Tc*512 f32) + 4 state bufs
    const size_t stateBytes = 4ull * NB * HD * sizeof(float);         // 512 KB
    const size_t perT = (size_t)NB*HD*sizeof(float) + (size_t)NB*NG*sizeof(float); // 655360 B
    long tcl = (ws_size > stateBytes) ? (long)((ws_size - stateBytes) / perT) : 1;
    if (tcl > TT) tcl = TT;
    if (tcl < 1)  tcl = 1;
    const int Tc = (int)tcl;   // derived from ws_size only -> deterministic

    float* h1c  = (float*)d_ws;
    float* xg1c = h1c  + (size_t)NB * Tc * HD;
    float* hs1  = xg1c + (size_t)NB * Tc * NG;
    float* cs1  = hs1 + NB*HD;
    float* hs2  = cs1 + NB*HD;
    float* cs2  = hs2 + NB*HD;
    float* h2c  = h1c;   // h1c is dead after K2 of the same chunk — reuse for h2

    for (int t0 = 0; t0 < TT; t0 += Tc) {
        const int len = (TT - t0 < Tc) ? (TT - t0) : Tc;
        lstm_layer0<<<dim3(NB), dim3(1024), 0, stream>>>(
            x, Wih0, Whh0, bih0, bhh0, h1c, hs1, cs1, t0, len);
        xgate_gemm<<<dim3(NB), dim3(1024), 0, stream>>>(
            h1c, Wih1, bih1, bhh1, xg1c, len);
        lstm_layer1<<<dim3(NB), dim3(1024), 0, stream>>>(
            xg1c, Whh1, h2c, hs2, cs2, t0, len);
        fc_head<<<dim3(NB), dim3(512), 0, stream>>>(
            h2c, fcw, fcb, y, t0, len);
    }
}

// Round 10
// 2458.590 us; speedup vs baseline: 1.5188x; 1.5188x over previous
//
#include <hip/hip_runtime.h>

#define NB 256      // batch
#define TT 1000     // total timesteps
#define HD 128      // hidden
#define NG 512      // 4*H, PyTorch gate order i,f,g,o
#define SS 8        // K2: timesteps per LDS slab

// 8 waves/block at 1 block/CU = exactly 2 waves/EU. Pinning (2,2) sets the
// allocator budget to 256 VGPR AND removes any higher occupancy target.
#define WGA __attribute__((amdgpu_flat_work_group_size(512,512), amdgpu_waves_per_eu(2,2)))

// 128-element dot, software-pipelined in 4-float4 groups. sched_barrier(0)
// after each group stops the scheduler from hoisting ALL 32 ds_read_b128 to
// the loop top (which spikes live pressure to ~280 and forces the weights
// into AGPR spills with a v_accvgpr_read tax per use). Loads of group g+1
// still overlap FMAs of group g within each region.
#define DOT128(h4, wv, A0, A1, A2, A3)                                        \
    {                                                                          \
        float4 c0=(h4)[0], c1=(h4)[1], c2=(h4)[2], c3=(h4)[3];                 \
        _Pragma("unroll")                                                      \
        for (int g = 0; g < 8; ++g) {                                          \
            float4 n0,n1,n2,n3;                                                \
            if (g < 7) { n0=(h4)[4*g+4]; n1=(h4)[4*g+5];                       \
                         n2=(h4)[4*g+6]; n3=(h4)[4*g+7]; }                     \
            A0 = fmaf(c0.x, wv[4*g+0].x, A0); A1 = fmaf(c0.y, wv[4*g+0].y, A1);\
            A2 = fmaf(c0.z, wv[4*g+0].z, A2); A3 = fmaf(c0.w, wv[4*g+0].w, A3);\
            A0 = fmaf(c1.x, wv[4*g+1].x, A0); A1 = fmaf(c1.y, wv[4*g+1].y, A1);\
            A2 = fmaf(c1.z, wv[4*g+1].z, A2); A3 = fmaf(c1.w, wv[4*g+1].w, A3);\
            A0 = fmaf(c2.x, wv[4*g+2].x, A0); A1 = fmaf(c2.y, wv[4*g+2].y, A1);\
            A2 = fmaf(c2.z, wv[4*g+2].z, A2); A3 = fmaf(c2.w, wv[4*g+2].w, A3);\
            A0 = fmaf(c3.x, wv[4*g+3].x, A0); A1 = fmaf(c3.y, wv[4*g+3].y, A1);\
            A2 = fmaf(c3.z, wv[4*g+3].z, A2); A3 = fmaf(c3.w, wv[4*g+3].w, A3);\
            __builtin_amdgcn_sched_barrier(0);                                 \
            if (g < 7) { c0=n0; c1=n1; c2=n2; c3=n3; }                         \
        }                                                                      \
    }

__device__ __forceinline__ float sigf(float x) {
    return 1.f / (1.f + __expf(-x));
}
__device__ __forceinline__ float tanhfast(float x) {
    float e = __expf(-2.f * x);                 // 2*sigmoid(2x)-1, NaN-safe
    return 2.f / (1.f + e) - 1.f;
}

// ---------------- K1: layer-0 recurrence ----------------
__global__ WGA
void lstm_layer0(const float* __restrict__ x,
                 const float* __restrict__ Wih, const float* __restrict__ Whh,
                 const float* __restrict__ bih, const float* __restrict__ bhh,
                 float* __restrict__ h1c,
                 float* __restrict__ hstate, float* __restrict__ cstate,
                 int t0, int len)
{
    __shared__ __align__(16) float h_lds[HD];
    __shared__ float gbuf[NG];
    __shared__ float x_lds[3 * TT];   // 12 KB
    const int j = threadIdx.x;
    const int b = blockIdx.x;

    float4 wv[HD/4];   // W_hh row j
    {
        const float4* wr = (const float4*)(Whh + (size_t)j * HD);
        #pragma unroll
        for (int q = 0; q < HD/4; ++q) wv[q] = wr[q];
    }
    const float wx0 = Wih[j*3+0], wx1 = Wih[j*3+1], wx2 = Wih[j*3+2];
    const float bias = bih[j] + bhh[j];

    for (int idx = j; idx < 3*len; idx += 512)
        x_lds[idx] = x[((size_t)b*TT + t0)*3 + idx];

    float c = 0.f, hcur = 0.f;
    if (j < HD) {
        if (t0 != 0) { hcur = hstate[b*HD+j]; c = cstate[b*HD+j]; }
        h_lds[j] = hcur;
    }
    __syncthreads();

    const int gtype = j >> 7;   // 0:i 1:f 2:g 3:o — wave-uniform
    for (int tc = 0; tc < len; ++tc) {
        float a0=0.f,a1=0.f,a2=0.f,a3=0.f;
        const float4* h4 = (const float4*)h_lds;   // uniform addr -> LDS broadcast
        DOT128(h4, wv, a0, a1, a2, a3);
        float acc = bias + ((a0+a1)+(a2+a3));
        acc = fmaf(wx0, x_lds[3*tc+0], acc);
        acc = fmaf(wx1, x_lds[3*tc+1], acc);
        acc = fmaf(wx2, x_lds[3*tc+2], acc);
        float act = (gtype == 2) ? tanhfast(acc) : sigf(acc);
        gbuf[j] = act;
        __syncthreads();                 // barrier A: gates visible
        if (j < HD) {
            float ig = gbuf[j], fg = gbuf[HD+j], gg = gbuf[2*HD+j], og = gbuf[3*HD+j];
            c = fmaf(fg, c, ig*gg);
            hcur = og * tanhfast(c);
            h_lds[j] = hcur;
            h1c[((size_t)b*len + tc)*HD + j] = hcur;
        }
        __syncthreads();                 // barrier B: new h visible
    }
    if (j < HD) { hstate[b*HD+j] = hcur; cstate[b*HD+j] = c; }
}

// ---------------- K2: xg1 = h1 @ W_ih_l1^T + biases ----------------
__global__ WGA
void xgate_gemm(const float* __restrict__ h1c,
                const float* __restrict__ Wih1,
                const float* __restrict__ bih1, const float* __restrict__ bhh1,
                float* __restrict__ xg1c, int len)
{
    __shared__ __align__(16) float hrows[SS][HD];   // 4 KB
    const int j = threadIdx.x;
    const int b = blockIdx.x;
    float4 wv[HD/4];
    {
        const float4* wr = (const float4*)(Wih1 + (size_t)j * HD);
        #pragma unroll
        for (int q = 0; q < HD/4; ++q) wv[q] = wr[q];
    }
    const float bias = bih1[j] + bhh1[j];

    for (int ts = 0; ts < len; ts += SS) {
        const int ns = (len - ts < SS) ? (len - ts) : SS;
        __syncthreads();   // previous slab's reads complete before overwrite
        for (int idx = j; idx < ns * HD; idx += 512)
            hrows[idx >> 7][idx & 127] = h1c[((size_t)b*len + ts)*HD + idx];
        __syncthreads();   // slab visible
        for (int s = 0; s < ns; ++s) {
            float a0=0.f,a1=0.f,a2=0.f,a3=0.f;
            const float4* h4 = (const float4*)hrows[s];   // uniform addr broadcast
            DOT128(h4, wv, a0, a1, a2, a3);
            xg1c[((size_t)b*len + ts + s)*NG + j] = bias + ((a0+a1)+(a2+a3));
        }
    }
}

// ---------------- K3: layer-1 recurrence (no FC head) ----------------
__global__ WGA
void lstm_layer1(const float* __restrict__ xg1c,
                 const float* __restrict__ Whh1,
                 float* __restrict__ h2c,
                 float* __restrict__ hstate, float* __restrict__ cstate,
                 int t0, int len)
{
    __shared__ __align__(16) float h_lds[HD];
    __shared__ float gbuf[NG];
    const int j = threadIdx.x;
    const int b = blockIdx.x;
    float4 wv[HD/4];   // W_hh_l1 row j
    {
        const float4* wr = (const float4*)(Whh1 + (size_t)j * HD);
        #pragma unroll
        for (int q = 0; q < HD/4; ++q) wv[q] = wr[q];
    }
    float c = 0.f, hcur = 0.f;
    if (j < HD) {
        if (t0 != 0) { hcur = hstate[b*HD+j]; c = cstate[b*HD+j]; }
        h_lds[j] = hcur;
    }
    __syncthreads();
    const int gtype = j >> 7;
    float xg_cur = xg1c[((size_t)b*len + 0)*NG + j];
    for (int tc = 0; tc < len; ++tc) {
        float xg_nxt = 0.f;
        if (tc+1 < len) xg_nxt = xg1c[((size_t)b*len + tc+1)*NG + j]; // prefetch
        float a0=0.f,a1=0.f,a2=0.f,a3=0.f;
        const float4* h4 = (const float4*)h_lds;
        DOT128(h4, wv, a0, a1, a2, a3);
        float acc = xg_cur + ((a0+a1)+(a2+a3));
        float act = (gtype == 2) ? tanhfast(acc) : sigf(acc);
        gbuf[j] = act;
        __syncthreads();                 // barrier A
        if (j < HD) {
            float ig = gbuf[j], fg = gbuf[HD+j], gg = gbuf[2*HD+j], og = gbuf[3*HD+j];
            c = fmaf(fg, c, ig*gg);
            hcur = og * tanhfast(c);
            h_lds[j] = hcur;
            h2c[((size_t)b*len + tc)*HD + j] = hcur;
        }
        __syncthreads();                 // barrier B
        xg_cur = xg_nxt;
    }
    if (j < HD) { hstate[b*HD+j] = hcur; cstate[b*HD+j] = c; }
}

// ---------------- K4: y = h2 @ fcw^T + fcb — wave-per-row, deterministic ----------------
__global__ __launch_bounds__(512, 1)
void fc_head(const float* __restrict__ h2c,
             const float* __restrict__ fcw, const float* __restrict__ fcb,
             float* __restrict__ y, int t0, int len)
{
    const int b = blockIdx.x;
    const int wid = threadIdx.x >> 6;   // 0..7
    const int lane = threadIdx.x & 63;
    const float f0a = fcw[0*HD+lane], f0b = fcw[0*HD+64+lane];
    const float f1a = fcw[1*HD+lane], f1b = fcw[1*HD+64+lane];
    const float f2a = fcw[2*HD+lane], f2b = fcw[2*HD+64+lane];
    const float fb = (lane < 3) ? fcb[lane] : 0.f;
    for (int tc = wid; tc < len; tc += 8) {
        const float* hp = h2c + ((size_t)b*len + tc)*HD;
        float ha = hp[lane], hb = hp[64+lane];
        float y0 = ha*f0a + hb*f0b;
        float y1 = ha*f1a + hb*f1b;
        float y2 = ha*f2a + hb*f2b;
        #pragma unroll
        for (int m = 1; m < 64; m <<= 1) {
            y0 += __shfl_xor(y0, m);
            y1 += __shfl_xor(y1, m);
            y2 += __shfl_xor(y2, m);
        }
        if (lane < 3) {
            float yv = (lane==0) ? y0 : (lane==1) ? y1 : y2;
            y[((size_t)b*TT + (t0+tc))*3 + lane] = yv + fb;
        }
    }
}

extern "C" void kernel_launch(void* const* d_in, const int* in_sizes, int n_in,
                              void* d_out, int out_size, void* d_ws, size_t ws_size,
                              hipStream_t stream)
{
    const float* x    = (const float*)d_in[0];
    const float* Wih0 = (const float*)d_in[1];
    const float* Whh0 = (const float*)d_in[2];
    const float* bih0 = (const float*)d_in[3];
    const float* bhh0 = (const float*)d_in[4];
    const float* Wih1 = (const float*)d_in[5];
    const float* Whh1 = (const float*)d_in[6];
    const float* bih1 = (const float*)d_in[7];
    const float* bhh1 = (const float*)d_in[8];
    const float* fcw  = (const float*)d_in[9];
    const float* fcb  = (const float*)d_in[10];
    float* y = (float*)d_out;

    // ws layout: h1 chunk (B*Tc*128 f32) + xg1 chunk (B*Tc*512 f32) + 4 state bufs
    const size_t stateBytes = 4ull * NB * HD * sizeof(float);         // 512 KB
    const size_t perT = (size_t)NB*HD*sizeof(float) + (size_t)NB*NG*sizeof(float); // 655360 B
    long tcl = (ws_size > stateBytes) ? (long)((ws_size - stateBytes) / perT) : 1;
    if (tcl > TT) tcl = TT;
    if (tcl < 1)  tcl = 1;
    const int Tc = (int)tcl;   // derived from ws_size only -> deterministic

    float* h1c  = (float*)d_ws;
    float* xg1c = h1c  + (size_t)NB * Tc * HD;
    float* hs1  = xg1c + (size_t)NB * Tc * NG;
    float* cs1  = hs1 + NB*HD;
    float* hs2  = cs1 + NB*HD;
    float* cs2  = hs2 + NB*HD;
    float* h2c  = h1c;   // h1c is dead after K2 of the same chunk — reuse for h2

    for (int t0 = 0; t0 < TT; t0 += Tc) {
        const int len = (TT - t0 < Tc) ? (TT - t0) : Tc;
        lstm_layer0<<<dim3(NB), dim3(512), 0, stream>>>(
            x, Wih0, Whh0, bih0, bhh0, h1c, hs1, cs1, t0, len);
        xgate_gemm<<<dim3(NB), dim3(512), 0, stream>>>(
            h1c, Wih1, bih1, bhh1, xg1c, len);
        lstm_layer1<<<dim3(NB), dim3(512), 0, stream>>>(
            xg1c, Whh1, h2c, hs2, cs2, t0, len);
        fc_head<<<dim3(NB), dim3(512), 0, stream>>>(
            h2c, fcw, fcb, y, t0, len);
    }
}